// Round 18
// baseline (24.583 us; speedup 1.0000x reference)
//
#include <hip/hip_runtime.h>

// Dihedral2Coord — R16 (1 molecule/wave, quat-only W64 DPP scan, E=S⊗conj(D),
// 2-stride translation chains) + NONTEMPORAL output stores.
// Evidence: R7 x6 FETCH_SIZE was ~26MB above the read model == out-buffer
// size -> L2 write-allocate fetches every store line from HBM first. nt
// stores bypass that, cutting ~25MB of waste HBM reads per call.
// (R17 fix: __builtin_nontemporal_store needs a NATIVE vector type, not
// HIP's float4 class -> cast through ext_vector_type(4) float.)

#define NK 128
#define NM 512
#define NMOL 4096
#define TPB 256
#define WPB 4        // waves per block, 1 molecule per wave
// grid = NMOL/WPB = 1024 -> 4 blocks/CU -> 16 waves/CU

typedef float vfloat4 __attribute__((ext_vector_type(4)));

struct Q4 { float w, x, y, z; };

__device__ __forceinline__ Q4 qmul(const Q4& a, const Q4& b) {
    Q4 r;
    r.w = a.w*b.w - a.x*b.x - a.y*b.y - a.z*b.z;
    r.x = a.w*b.x + a.x*b.w + a.y*b.z - a.z*b.y;
    r.y = a.w*b.y - a.x*b.z + a.y*b.w + a.z*b.x;
    r.z = a.w*b.z + a.x*b.y - a.y*b.x + a.z*b.w;
    return r;
}

__device__ __forceinline__ void qrotv(const Q4& q, float vx, float vy, float vz,
                                      float& ox, float& oy, float& oz) {
    const float ux = q.y*vz - q.z*vy + q.w*vx;
    const float uy = q.z*vx - q.x*vz + q.w*vy;
    const float uz = q.x*vy - q.y*vx + q.w*vz;
    ox = vx + 2.f*(q.y*uz - q.z*uy);
    oy = vy + 2.f*(q.z*ux - q.x*uz);
    oz = vz + 2.f*(q.x*uy - q.y*ux);
}

// DPP: ROW_SHR:N = 0x110+N ; ROW_BCAST15 = 0x142 ; ROW_BCAST31 = 0x143.
template <int CTRL, int RMASK>
__device__ __forceinline__ float dpp_mov(float x) {
    return __int_as_float(__builtin_amdgcn_update_dpp(
        0, __float_as_int(x), CTRL, RMASK, 0xF, true));
}

// NT store of a float4 value through a native-vector pointer
__device__ __forceinline__ void nt_store4(float4* p, float x, float y, float z, float w) {
    vfloat4 v; v.x = x; v.y = y; v.z = z; v.w = w;
    __builtin_nontemporal_store(v, (vfloat4*)p);
}
__device__ __forceinline__ void nt_store4v(float4* p, const float4 v) {
    nt_store4(p, v.x, v.y, v.z, v.w);
}

// Step-quat for step 2l+j (validated sphi/cphi formula, R10-R16; quat only)
#define BUILD_Q(j, OUT) do {                                                  \
    const float cxx = ny[(j)+1]*nz[(j)] - nz[(j)+1]*ny[(j)];                  \
    const float cxy = nz[(j)+1]*nx[(j)] - nx[(j)+1]*nz[(j)];                  \
    const float cxz = nx[(j)+1]*ny[(j)] - ny[(j)+1]*nx[(j)];                  \
    const float g   = cxx*vx[(j)+1] + cxy*vy[(j)+1] + cxz*vz[(j)+1];          \
    const float dnn = nx[(j)]*nx[(j)+1] + ny[(j)]*ny[(j)+1] + nz[(j)]*nz[(j)+1]; \
    const float r12 = rsqrtf(fmaxf(Ln[(j)]*Ln[(j)+1], 1e-30f));               \
    const float ira = rsqrtf(fmaxf(Lv[(j)+1], 1e-24f));                       \
    const float cphi = dnn*r12, sphi = g*r12*ira;                             \
    const float sth = __sinf(th[(j)]), cth = __cosf(th[(j)]);                 \
    const float c = cth*cphi - sth*sphi, s = sth*cphi + cth*sphi;             \
    const float hc = sqrtf(fmaxf(0.f, 0.5f*(1.f + c)));                       \
    const float hs = copysignf(sqrtf(fmaxf(0.f, 0.5f*(1.f - c))), s);         \
    const float hsa = hs*ira;                                                 \
    OUT.w = hc; OUT.x = vx[(j)+1]*hsa; OUT.y = vy[(j)+1]*hsa; OUT.z = vz[(j)+1]*hsa; \
} while (0)

__global__ __launch_bounds__(TPB, 4) void dihedral_w64_nt_kernel(
    const float* __restrict__ theta,  // (NMOL, NK)
    const float* __restrict__ pos0,   // (NMOL, NM, 3)
    float* __restrict__ out)          // (NMOL, NM, 3)
{
    const int tid  = threadIdx.x;
    const int lane = tid & 63;
    const int wid  = tid >> 6;
    const int mol  = blockIdx.x * WPB + wid;

    const float4* __restrict__ pb4 = (const float4*)(pos0 + (size_t)mol * (NM*3));
    float4*       __restrict__ ob4 = (float4*)(out  + (size_t)mol * (NM*3));

    __shared__ float sAm[WPB][400];   // pos0 atoms 0..131
    __shared__ float sOm[WPB][400];   // final atoms 0..131
    float* __restrict__ sa   = sAm[wid];
    float* __restrict__ sout = sOm[wid];

    // ---- issue ALL global loads up front ----
    const bool ex   = (lane < 35);
    const bool has2 = (lane < 31);   // tail tasks 64..94
    float4 h0 = pb4[lane];
    float4 h1; if (ex) h1 = pb4[64 + lane];
    const float2 th2 = ((const float2*)(theta + (size_t)mol * NK))[lane];
    float4 T0a, T0b, T0c, T1a, T1b, T1c;
    { const int b = 99 + 3*lane; T0a = pb4[b]; T0b = pb4[b+1]; T0c = pb4[b+2]; }
    if (has2) { const int b = 99 + 3*(64 + lane); T1a = pb4[b]; T1b = pb4[b+1]; T1c = pb4[b+2]; }

    // stage head (same-wave DS ordering, no barrier)
    float4* sa4 = (float4*)sa;
    sa4[lane] = h0;
    if (ex) sa4[64 + lane] = h1;

    // lane l: atoms 2l..2l+4 (15 floats)
    float A[16];
    {
        const float2* ap2 = (const float2*)&sa[lane * 6];
        #pragma unroll
        for (int i = 0; i < 7; ++i) { const float2 v = ap2[i]; A[2*i] = v.x; A[2*i+1] = v.y; }
        A[14] = sa[lane * 6 + 14];
    }

    // bonds / normals for the 2 steps
    float vx[4], vy[4], vz[4];
    #pragma unroll
    for (int i = 0; i < 4; ++i) {
        vx[i] = A[3*i+3] - A[3*i];
        vy[i] = A[3*i+4] - A[3*i+1];
        vz[i] = A[3*i+5] - A[3*i+2];
    }
    float nx[3], ny[3], nz[3], Ln[3];
    #pragma unroll
    for (int i = 0; i < 3; ++i) {
        nx[i] = vy[i]*vz[i+1] - vz[i]*vy[i+1];
        ny[i] = vz[i]*vx[i+1] - vx[i]*vz[i+1];
        nz[i] = vx[i]*vy[i+1] - vy[i]*vx[i+1];
        Ln[i] = nx[i]*nx[i] + ny[i]*ny[i] + nz[i]*nz[i];
    }
    float Lv[3];
    #pragma unroll
    for (int i = 1; i < 3; ++i) Lv[i] = vx[i]*vx[i] + vy[i]*vy[i] + vz[i]*vz[i];
    const float th[2] = {th2.x, th2.y};

    // ---- build 2 step quats; D = q0⊗q1 ----
    Q4 q0, q1;
    BUILD_Q(0, q0); BUILD_Q(1, q1);
    const Q4 D = qmul(q0, q1);
    Q4 S = D;

    // ---- 6-round W64 inclusive quat scan via DPP ----
    const int rowi = lane & 15;
    #define QSCAN_ROUND(CTRL, COND)                                          \
    do {                                                                     \
        Q4 Qp;                                                               \
        Qp.w = dpp_mov<CTRL, 0xF>(S.w); Qp.x = dpp_mov<CTRL, 0xF>(S.x);      \
        Qp.y = dpp_mov<CTRL, 0xF>(S.y); Qp.z = dpp_mov<CTRL, 0xF>(S.z);      \
        if (COND) S = qmul(Qp, S);                                           \
    } while (0)
    QSCAN_ROUND(0x111, rowi >= 1);
    QSCAN_ROUND(0x112, rowi >= 2);
    QSCAN_ROUND(0x114, rowi >= 4);
    QSCAN_ROUND(0x118, rowi >= 8);
    QSCAN_ROUND(0x142, (lane & 16) != 0);   // rows 1,3: prepend lower-row total
    QSCAN_ROUND(0x143, (lane & 32) != 0);   // rows 2,3: prepend rows0-1 total
    #undef QSCAN_ROUND

    // exclusive prefix: E = S ⊗ conj(D)  (unit quats; lane0 -> identity)
    Q4 Dc; Dc.w = D.w; Dc.x = -D.x; Dc.y = -D.y; Dc.z = -D.z;
    const Q4 E  = qmul(S, Dc);
    const Q4 Pe = qmul(E, q0);          // R(P_{2l});  R(P_{2l+1}) = S

    // ---- d = R(P_k)·(pos0[k+3]-pos0[k+1]) ----
    float dex, dey, dez, dox, doy, doz;
    qrotv(Pe, A[9]-A[3],  A[10]-A[4], A[11]-A[5], dex, dey, dez);
    qrotv(S,  A[12]-A[6], A[13]-A[7], A[14]-A[8], dox, doy, doz);

    // ---- two float3 inclusive prefix sums via DPP (unconditional adds) ----
    float sex = dex, sey = dey, sez = dez;
    float sox = dox, soy = doy, soz = doz;
    #define SUM_ROUND(CTRL, RM)                                              \
    do {                                                                     \
        sex += dpp_mov<CTRL, RM>(sex); sey += dpp_mov<CTRL, RM>(sey);        \
        sez += dpp_mov<CTRL, RM>(sez);                                       \
        sox += dpp_mov<CTRL, RM>(sox); soy += dpp_mov<CTRL, RM>(soy);        \
        soz += dpp_mov<CTRL, RM>(soz);                                       \
    } while (0)
    SUM_ROUND(0x111, 0xF);
    SUM_ROUND(0x112, 0xF);
    SUM_ROUND(0x114, 0xF);
    SUM_ROUND(0x118, 0xF);
    SUM_ROUND(0x142, 0xA);   // rows 1,3 add lower-row total; rows 0,2 add 0
    SUM_ROUND(0x143, 0xC);   // rows 2,3 add rows0-1 total; rows 0,1 add 0
    #undef SUM_ROUND

    // final[2l+3] = pos0[1] + Se ; final[2l+4] = pos0[2] + So
    const float p1x = sa[3], p1y = sa[4], p1z = sa[5];
    const float p2x = sa[6], p2y = sa[7], p2z = sa[8];
    const float fex = p1x + sex, fey = p1y + sey, fez = p1z + sez;
    const float fox = p2x + sox, foy = p2y + soy, foz = p2z + soz;

    {
        float* op = &sout[6*lane + 9];
        op[0] = fex; op[1] = fey; op[2] = fez;   // atom 2l+3
        op[3] = fox; op[4] = foy; op[5] = foz;   // atom 2l+4
    }
    if (lane < 9) sout[lane] = sa[lane];   // atoms 0..2 never move

    // ---- F = P_127 (S@63); translation from final[130] = fo@63 ----
    float tFx = 0.f, tFy = 0.f, tFz = 0.f;
    if (lane == 63) {
        float rx, ry, rz;
        qrotv(S, sa[390], sa[391], sa[392], rx, ry, rz);   // R_F·pos0[130]
        tFx = fox - rx; tFy = foy - ry; tFz = foz - rz;
        // atom 131 = F(pos0[131])
        qrotv(S, sa[393], sa[394], sa[395], rx, ry, rz);
        sout[393] = rx + tFx; sout[394] = ry + tFy; sout[395] = rz + tFz;
    }
    Q4 Fq;
    Fq.w = __shfl(S.w, 63, 64); Fq.x = __shfl(S.x, 63, 64);
    Fq.y = __shfl(S.y, 63, 64); Fq.z = __shfl(S.z, 63, 64);
    const float Ftx = __shfl(tFx, 63, 64), Fty = __shfl(tFy, 63, 64), Ftz = __shfl(tFz, 63, 64);
    const float f00 = 1.f - 2.f*(Fq.y*Fq.y + Fq.z*Fq.z);
    const float f01 = 2.f*(Fq.x*Fq.y - Fq.w*Fq.z);
    const float f02 = 2.f*(Fq.x*Fq.z + Fq.w*Fq.y);
    const float f10 = 2.f*(Fq.x*Fq.y + Fq.w*Fq.z);
    const float f11 = 1.f - 2.f*(Fq.x*Fq.x + Fq.z*Fq.z);
    const float f12 = 2.f*(Fq.y*Fq.z - Fq.w*Fq.x);
    const float f20 = 2.f*(Fq.x*Fq.z - Fq.w*Fq.y);
    const float f21 = 2.f*(Fq.y*Fq.z + Fq.w*Fq.x);
    const float f22 = 1.f - 2.f*(Fq.x*Fq.x + Fq.y*Fq.y);

    // ---- store head (99 f4), nontemporal ----
    const float4* so4 = (const float4*)sout;
    nt_store4v(&ob4[lane], so4[lane]);
    if (ex) nt_store4v(&ob4[64 + lane], so4[64 + lane]);

    // ---- tail: 95 f4-triples, up to 2 per lane, nontemporal stores ----
    #define TAIL_EMIT(b, va, vb, vc)                                          \
    do {                                                                      \
        const float x0=va.x, y0=va.y, z0=va.z;                                \
        const float x1=va.w, y1=vb.x, z1=vb.y;                                \
        const float x2=vb.z, y2=vb.w, z2=vc.x;                                \
        const float x3=vc.y, y3=vc.z, z3=vc.w;                                \
        nt_store4(&ob4[(b)],                                                  \
                  f00*x0+f01*y0+f02*z0+Ftx, f10*x0+f11*y0+f12*z0+Fty,         \
                  f20*x0+f21*y0+f22*z0+Ftz, f00*x1+f01*y1+f02*z1+Ftx);        \
        nt_store4(&ob4[(b)+1],                                                \
                  f10*x1+f11*y1+f12*z1+Fty, f20*x1+f21*y1+f22*z1+Ftz,         \
                  f00*x2+f01*y2+f02*z2+Ftx, f10*x2+f11*y2+f12*z2+Fty);        \
        nt_store4(&ob4[(b)+2],                                                \
                  f20*x2+f21*y2+f22*z2+Ftz, f00*x3+f01*y3+f02*z3+Ftx,         \
                  f10*x3+f11*y3+f12*z3+Fty, f20*x3+f21*y3+f22*z3+Ftz);        \
    } while (0)

    TAIL_EMIT(99 + 3*lane, T0a, T0b, T0c);
    if (has2) TAIL_EMIT(99 + 3*(64 + lane), T1a, T1b, T1c);
    #undef TAIL_EMIT
}

extern "C" void kernel_launch(void* const* d_in, const int* in_sizes, int n_in,
                              void* d_out, int out_size, void* d_ws, size_t ws_size,
                              hipStream_t stream) {
    const float* theta = (const float*)d_in[0];  // input (N,K) fp32
    const float* pos0  = (const float*)d_in[1];  // pos0 (N,M,3) fp32
    float* out = (float*)d_out;                  // (N,M,3) fp32
    dihedral_w64_nt_kernel<<<NMOL / WPB, TPB, 0, stream>>>(theta, pos0, out);
}

// Round 19
// 16.320 us; speedup vs baseline: 1.5063x; 1.5063x over previous
//
#include <hip/hip_runtime.h>

// Dihedral2Coord — R16 math (quat-only W64 DPP scan, E=S⊗conj(D), 2-stride
// translation chains, plain f4 stores) with ONE-WAVE BLOCKS (grid=4096).
// Single-wave blocks let the CU scheduler refill slots per-wave as each
// molecule finishes -> resident waves spread across load/compute/store
// phases instead of the grid-wide lockstep burst-bubble-burst pattern.

#define NK 128
#define NM 512
#define NMOL 4096
#define TPB 64       // ONE wave per block, one molecule per block

struct Q4 { float w, x, y, z; };

__device__ __forceinline__ Q4 qmul(const Q4& a, const Q4& b) {
    Q4 r;
    r.w = a.w*b.w - a.x*b.x - a.y*b.y - a.z*b.z;
    r.x = a.w*b.x + a.x*b.w + a.y*b.z - a.z*b.y;
    r.y = a.w*b.y - a.x*b.z + a.y*b.w + a.z*b.x;
    r.z = a.w*b.z + a.x*b.y - a.y*b.x + a.z*b.w;
    return r;
}

__device__ __forceinline__ void qrotv(const Q4& q, float vx, float vy, float vz,
                                      float& ox, float& oy, float& oz) {
    const float ux = q.y*vz - q.z*vy + q.w*vx;
    const float uy = q.z*vx - q.x*vz + q.w*vy;
    const float uz = q.x*vy - q.y*vx + q.w*vz;
    ox = vx + 2.f*(q.y*uz - q.z*uy);
    oy = vy + 2.f*(q.z*ux - q.x*uz);
    oz = vz + 2.f*(q.x*uy - q.y*ux);
}

// DPP: ROW_SHR:N = 0x110+N ; ROW_BCAST15 = 0x142 ; ROW_BCAST31 = 0x143.
template <int CTRL, int RMASK>
__device__ __forceinline__ float dpp_mov(float x) {
    return __int_as_float(__builtin_amdgcn_update_dpp(
        0, __float_as_int(x), CTRL, RMASK, 0xF, true));
}

// Step-quat for step 2l+j (validated sphi/cphi formula, R10-R16; quat only)
#define BUILD_Q(j, OUT) do {                                                  \
    const float cxx = ny[(j)+1]*nz[(j)] - nz[(j)+1]*ny[(j)];                  \
    const float cxy = nz[(j)+1]*nx[(j)] - nx[(j)+1]*nz[(j)];                  \
    const float cxz = nx[(j)+1]*ny[(j)] - ny[(j)+1]*nx[(j)];                  \
    const float g   = cxx*vx[(j)+1] + cxy*vy[(j)+1] + cxz*vz[(j)+1];          \
    const float dnn = nx[(j)]*nx[(j)+1] + ny[(j)]*ny[(j)+1] + nz[(j)]*nz[(j)+1]; \
    const float r12 = rsqrtf(fmaxf(Ln[(j)]*Ln[(j)+1], 1e-30f));               \
    const float ira = rsqrtf(fmaxf(Lv[(j)+1], 1e-24f));                       \
    const float cphi = dnn*r12, sphi = g*r12*ira;                             \
    const float sth = __sinf(th[(j)]), cth = __cosf(th[(j)]);                 \
    const float c = cth*cphi - sth*sphi, s = sth*cphi + cth*sphi;             \
    const float hc = sqrtf(fmaxf(0.f, 0.5f*(1.f + c)));                       \
    const float hs = copysignf(sqrtf(fmaxf(0.f, 0.5f*(1.f - c))), s);         \
    const float hsa = hs*ira;                                                 \
    OUT.w = hc; OUT.x = vx[(j)+1]*hsa; OUT.y = vy[(j)+1]*hsa; OUT.z = vz[(j)+1]*hsa; \
} while (0)

__global__ __launch_bounds__(TPB) void dihedral_w64_1wb_kernel(
    const float* __restrict__ theta,  // (NMOL, NK)
    const float* __restrict__ pos0,   // (NMOL, NM, 3)
    float* __restrict__ out)          // (NMOL, NM, 3)
{
    const int lane = threadIdx.x;
    const int mol  = blockIdx.x;

    const float4* __restrict__ pb4 = (const float4*)(pos0 + (size_t)mol * (NM*3));
    float4*       __restrict__ ob4 = (float4*)(out  + (size_t)mol * (NM*3));

    __shared__ float sa[400];     // pos0 atoms 0..131
    __shared__ float sout[400];   // final atoms 0..131

    // ---- issue ALL global loads up front ----
    const bool ex   = (lane < 35);
    const bool has2 = (lane < 31);   // tail tasks 64..94
    float4 h0 = pb4[lane];
    float4 h1; if (ex) h1 = pb4[64 + lane];
    const float2 th2 = ((const float2*)(theta + (size_t)mol * NK))[lane];
    float4 T0a, T0b, T0c, T1a, T1b, T1c;
    { const int b = 99 + 3*lane; T0a = pb4[b]; T0b = pb4[b+1]; T0c = pb4[b+2]; }
    if (has2) { const int b = 99 + 3*(64 + lane); T1a = pb4[b]; T1b = pb4[b+1]; T1c = pb4[b+2]; }

    // stage head (same-wave DS ordering, no barrier)
    float4* sa4 = (float4*)sa;
    sa4[lane] = h0;
    if (ex) sa4[64 + lane] = h1;

    // lane l: atoms 2l..2l+4 (15 floats)
    float A[16];
    {
        const float2* ap2 = (const float2*)&sa[lane * 6];
        #pragma unroll
        for (int i = 0; i < 7; ++i) { const float2 v = ap2[i]; A[2*i] = v.x; A[2*i+1] = v.y; }
        A[14] = sa[lane * 6 + 14];
    }

    // bonds / normals for the 2 steps
    float vx[4], vy[4], vz[4];
    #pragma unroll
    for (int i = 0; i < 4; ++i) {
        vx[i] = A[3*i+3] - A[3*i];
        vy[i] = A[3*i+4] - A[3*i+1];
        vz[i] = A[3*i+5] - A[3*i+2];
    }
    float nx[3], ny[3], nz[3], Ln[3];
    #pragma unroll
    for (int i = 0; i < 3; ++i) {
        nx[i] = vy[i]*vz[i+1] - vz[i]*vy[i+1];
        ny[i] = vz[i]*vx[i+1] - vx[i]*vz[i+1];
        nz[i] = vx[i]*vy[i+1] - vy[i]*vx[i+1];
        Ln[i] = nx[i]*nx[i] + ny[i]*ny[i] + nz[i]*nz[i];
    }
    float Lv[3];
    #pragma unroll
    for (int i = 1; i < 3; ++i) Lv[i] = vx[i]*vx[i] + vy[i]*vy[i] + vz[i]*vz[i];
    const float th[2] = {th2.x, th2.y};

    // ---- build 2 step quats; D = q0⊗q1 ----
    Q4 q0, q1;
    BUILD_Q(0, q0); BUILD_Q(1, q1);
    const Q4 D = qmul(q0, q1);
    Q4 S = D;

    // ---- 6-round W64 inclusive quat scan via DPP ----
    const int rowi = lane & 15;
    #define QSCAN_ROUND(CTRL, COND)                                          \
    do {                                                                     \
        Q4 Qp;                                                               \
        Qp.w = dpp_mov<CTRL, 0xF>(S.w); Qp.x = dpp_mov<CTRL, 0xF>(S.x);      \
        Qp.y = dpp_mov<CTRL, 0xF>(S.y); Qp.z = dpp_mov<CTRL, 0xF>(S.z);      \
        if (COND) S = qmul(Qp, S);                                           \
    } while (0)
    QSCAN_ROUND(0x111, rowi >= 1);
    QSCAN_ROUND(0x112, rowi >= 2);
    QSCAN_ROUND(0x114, rowi >= 4);
    QSCAN_ROUND(0x118, rowi >= 8);
    QSCAN_ROUND(0x142, (lane & 16) != 0);   // rows 1,3: prepend lower-row total
    QSCAN_ROUND(0x143, (lane & 32) != 0);   // rows 2,3: prepend rows0-1 total
    #undef QSCAN_ROUND

    // exclusive prefix: E = S ⊗ conj(D)  (unit quats; lane0 -> identity)
    Q4 Dc; Dc.w = D.w; Dc.x = -D.x; Dc.y = -D.y; Dc.z = -D.z;
    const Q4 E  = qmul(S, Dc);
    const Q4 Pe = qmul(E, q0);          // R(P_{2l});  R(P_{2l+1}) = S

    // ---- d = R(P_k)·(pos0[k+3]-pos0[k+1]) ----
    float dex, dey, dez, dox, doy, doz;
    qrotv(Pe, A[9]-A[3],  A[10]-A[4], A[11]-A[5], dex, dey, dez);
    qrotv(S,  A[12]-A[6], A[13]-A[7], A[14]-A[8], dox, doy, doz);

    // ---- two float3 inclusive prefix sums via DPP (unconditional adds) ----
    float sex = dex, sey = dey, sez = dez;
    float sox = dox, soy = doy, soz = doz;
    #define SUM_ROUND(CTRL, RM)                                              \
    do {                                                                     \
        sex += dpp_mov<CTRL, RM>(sex); sey += dpp_mov<CTRL, RM>(sey);        \
        sez += dpp_mov<CTRL, RM>(sez);                                       \
        sox += dpp_mov<CTRL, RM>(sox); soy += dpp_mov<CTRL, RM>(soy);        \
        soz += dpp_mov<CTRL, RM>(soz);                                       \
    } while (0)
    SUM_ROUND(0x111, 0xF);
    SUM_ROUND(0x112, 0xF);
    SUM_ROUND(0x114, 0xF);
    SUM_ROUND(0x118, 0xF);
    SUM_ROUND(0x142, 0xA);   // rows 1,3 add lower-row total; rows 0,2 add 0
    SUM_ROUND(0x143, 0xC);   // rows 2,3 add rows0-1 total; rows 0,1 add 0
    #undef SUM_ROUND

    // final[2l+3] = pos0[1] + Se ; final[2l+4] = pos0[2] + So
    const float p1x = sa[3], p1y = sa[4], p1z = sa[5];
    const float p2x = sa[6], p2y = sa[7], p2z = sa[8];
    const float fex = p1x + sex, fey = p1y + sey, fez = p1z + sez;
    const float fox = p2x + sox, foy = p2y + soy, foz = p2z + soz;

    {
        float* op = &sout[6*lane + 9];
        op[0] = fex; op[1] = fey; op[2] = fez;   // atom 2l+3
        op[3] = fox; op[4] = foy; op[5] = foz;   // atom 2l+4
    }
    if (lane < 9) sout[lane] = sa[lane];   // atoms 0..2 never move

    // ---- F = P_127 (S@63); translation from final[130] = fo@63 ----
    float tFx = 0.f, tFy = 0.f, tFz = 0.f;
    if (lane == 63) {
        float rx, ry, rz;
        qrotv(S, sa[390], sa[391], sa[392], rx, ry, rz);   // R_F·pos0[130]
        tFx = fox - rx; tFy = foy - ry; tFz = foz - rz;
        // atom 131 = F(pos0[131])
        qrotv(S, sa[393], sa[394], sa[395], rx, ry, rz);
        sout[393] = rx + tFx; sout[394] = ry + tFy; sout[395] = rz + tFz;
    }
    Q4 Fq;
    Fq.w = __shfl(S.w, 63, 64); Fq.x = __shfl(S.x, 63, 64);
    Fq.y = __shfl(S.y, 63, 64); Fq.z = __shfl(S.z, 63, 64);
    const float Ftx = __shfl(tFx, 63, 64), Fty = __shfl(tFy, 63, 64), Ftz = __shfl(tFz, 63, 64);
    const float f00 = 1.f - 2.f*(Fq.y*Fq.y + Fq.z*Fq.z);
    const float f01 = 2.f*(Fq.x*Fq.y - Fq.w*Fq.z);
    const float f02 = 2.f*(Fq.x*Fq.z + Fq.w*Fq.y);
    const float f10 = 2.f*(Fq.x*Fq.y + Fq.w*Fq.z);
    const float f11 = 1.f - 2.f*(Fq.x*Fq.x + Fq.z*Fq.z);
    const float f12 = 2.f*(Fq.y*Fq.z - Fq.w*Fq.x);
    const float f20 = 2.f*(Fq.x*Fq.z - Fq.w*Fq.y);
    const float f21 = 2.f*(Fq.y*Fq.z + Fq.w*Fq.x);
    const float f22 = 1.f - 2.f*(Fq.x*Fq.x + Fq.y*Fq.y);

    // ---- store head (99 f4) ----
    const float4* so4 = (const float4*)sout;
    ob4[lane] = so4[lane];
    if (ex) ob4[64 + lane] = so4[64 + lane];

    // ---- tail: 95 f4-triples, up to 2 per lane, data already in registers ----
    #define TAIL_EMIT(b, va, vb, vc)                                          \
    do {                                                                      \
        const float x0=va.x, y0=va.y, z0=va.z;                                \
        const float x1=va.w, y1=vb.x, z1=vb.y;                                \
        const float x2=vb.z, y2=vb.w, z2=vc.x;                                \
        const float x3=vc.y, y3=vc.z, z3=vc.w;                                \
        float4 o0, o1, o2;                                                    \
        o0.x = f00*x0+f01*y0+f02*z0+Ftx; o0.y = f10*x0+f11*y0+f12*z0+Fty;     \
        o0.z = f20*x0+f21*y0+f22*z0+Ftz; o0.w = f00*x1+f01*y1+f02*z1+Ftx;     \
        o1.x = f10*x1+f11*y1+f12*z1+Fty; o1.y = f20*x1+f21*y1+f22*z1+Ftz;     \
        o1.z = f00*x2+f01*y2+f02*z2+Ftx; o1.w = f10*x2+f11*y2+f12*z2+Fty;     \
        o2.x = f20*x2+f21*y2+f22*z2+Ftz; o2.y = f00*x3+f01*y3+f02*z3+Ftx;     \
        o2.z = f10*x3+f11*y3+f12*z3+Fty; o2.w = f20*x3+f21*y3+f22*z3+Ftz;     \
        ob4[(b)] = o0; ob4[(b)+1] = o1; ob4[(b)+2] = o2;                      \
    } while (0)

    TAIL_EMIT(99 + 3*lane, T0a, T0b, T0c);
    if (has2) TAIL_EMIT(99 + 3*(64 + lane), T1a, T1b, T1c);
    #undef TAIL_EMIT
}

extern "C" void kernel_launch(void* const* d_in, const int* in_sizes, int n_in,
                              void* d_out, int out_size, void* d_ws, size_t ws_size,
                              hipStream_t stream) {
    const float* theta = (const float*)d_in[0];  // input (N,K) fp32
    const float* pos0  = (const float*)d_in[1];  // pos0 (N,M,3) fp32
    float* out = (float*)d_out;                  // (N,M,3) fp32
    dihedral_w64_1wb_kernel<<<NMOL, TPB, 0, stream>>>(theta, pos0, out);
}

// Round 20
// 15.865 us; speedup vs baseline: 1.5496x; 1.0287x over previous
//
#include <hip/hip_runtime.h>

// Dihedral2Coord — R19 (1-wave blocks, quat-only W64 DPP scan, E=S⊗conj(D),
// 2-stride translation chains) + FULLY-COALESCED tail via LDS bounce.
// Old tail: f4 accesses at 48B stride -> ~48 lines touched per instruction
// (3x the transactions of coalesced). New: 5 coalesced f4 loads -> LDS ->
// in-place float-granularity transform (stride-3 = 2 lanes/bank = free) ->
// 5 coalesced f4 stores.

#define NK 128
#define NM 512
#define NMOL 4096
#define TPB 64       // ONE wave per block, one molecule per block
#define TAIL_F4 285  // f4 indices 99..383 (atoms 132..511)

struct Q4 { float w, x, y, z; };

__device__ __forceinline__ Q4 qmul(const Q4& a, const Q4& b) {
    Q4 r;
    r.w = a.w*b.w - a.x*b.x - a.y*b.y - a.z*b.z;
    r.x = a.w*b.x + a.x*b.w + a.y*b.z - a.z*b.y;
    r.y = a.w*b.y - a.x*b.z + a.y*b.w + a.z*b.x;
    r.z = a.w*b.z + a.x*b.y - a.y*b.x + a.z*b.w;
    return r;
}

__device__ __forceinline__ void qrotv(const Q4& q, float vx, float vy, float vz,
                                      float& ox, float& oy, float& oz) {
    const float ux = q.y*vz - q.z*vy + q.w*vx;
    const float uy = q.z*vx - q.x*vz + q.w*vy;
    const float uz = q.x*vy - q.y*vx + q.w*vz;
    ox = vx + 2.f*(q.y*uz - q.z*uy);
    oy = vy + 2.f*(q.z*ux - q.x*uz);
    oz = vz + 2.f*(q.x*uy - q.y*ux);
}

// DPP: ROW_SHR:N = 0x110+N ; ROW_BCAST15 = 0x142 ; ROW_BCAST31 = 0x143.
template <int CTRL, int RMASK>
__device__ __forceinline__ float dpp_mov(float x) {
    return __int_as_float(__builtin_amdgcn_update_dpp(
        0, __float_as_int(x), CTRL, RMASK, 0xF, true));
}

// Step-quat for step 2l+j (validated sphi/cphi formula, R10-R19; quat only)
#define BUILD_Q(j, OUT) do {                                                  \
    const float cxx = ny[(j)+1]*nz[(j)] - nz[(j)+1]*ny[(j)];                  \
    const float cxy = nz[(j)+1]*nx[(j)] - nx[(j)+1]*nz[(j)];                  \
    const float cxz = nx[(j)+1]*ny[(j)] - ny[(j)+1]*nx[(j)];                  \
    const float g   = cxx*vx[(j)+1] + cxy*vy[(j)+1] + cxz*vz[(j)+1];          \
    const float dnn = nx[(j)]*nx[(j)+1] + ny[(j)]*ny[(j)+1] + nz[(j)]*nz[(j)+1]; \
    const float r12 = rsqrtf(fmaxf(Ln[(j)]*Ln[(j)+1], 1e-30f));               \
    const float ira = rsqrtf(fmaxf(Lv[(j)+1], 1e-24f));                       \
    const float cphi = dnn*r12, sphi = g*r12*ira;                             \
    const float sth = __sinf(th[(j)]), cth = __cosf(th[(j)]);                 \
    const float c = cth*cphi - sth*sphi, s = sth*cphi + cth*sphi;             \
    const float hc = sqrtf(fmaxf(0.f, 0.5f*(1.f + c)));                       \
    const float hs = copysignf(sqrtf(fmaxf(0.f, 0.5f*(1.f - c))), s);         \
    const float hsa = hs*ira;                                                 \
    OUT.w = hc; OUT.x = vx[(j)+1]*hsa; OUT.y = vy[(j)+1]*hsa; OUT.z = vz[(j)+1]*hsa; \
} while (0)

__global__ __launch_bounds__(TPB) void dihedral_w64_coal_kernel(
    const float* __restrict__ theta,  // (NMOL, NK)
    const float* __restrict__ pos0,   // (NMOL, NM, 3)
    float* __restrict__ out)          // (NMOL, NM, 3)
{
    const int lane = threadIdx.x;
    const int mol  = blockIdx.x;

    const float4* __restrict__ pb4 = (const float4*)(pos0 + (size_t)mol * (NM*3));
    float4*       __restrict__ ob4 = (float4*)(out  + (size_t)mol * (NM*3));

    __shared__ float sa[400];              // pos0 atoms 0..131
    __shared__ float sout[400];            // final atoms 0..131
    __shared__ float st[TAIL_F4 * 4];      // tail f4s 99..383 (atoms 132..511)

    // ---- issue ALL global loads up front (all coalesced) ----
    const bool ex = (lane < 35);
    float4 h0 = pb4[lane];
    float4 h1; if (ex) h1 = pb4[64 + lane];
    const float2 th2 = ((const float2*)(theta + (size_t)mol * NK))[lane];
    float4 Tr0 = pb4[99 + lane];
    float4 Tr1 = pb4[99 + 64 + lane];
    float4 Tr2 = pb4[99 + 128 + lane];
    float4 Tr3 = pb4[99 + 192 + lane];
    float4 Tr4; const bool hasT4 = (lane < TAIL_F4 - 256);  // lane < 29
    if (hasT4) Tr4 = pb4[99 + 256 + lane];

    // stage head (same-wave DS ordering, no barrier)
    float4* sa4 = (float4*)sa;
    sa4[lane] = h0;
    if (ex) sa4[64 + lane] = h1;

    // lane l: atoms 2l..2l+4 (15 floats)
    float A[16];
    {
        const float2* ap2 = (const float2*)&sa[lane * 6];
        #pragma unroll
        for (int i = 0; i < 7; ++i) { const float2 v = ap2[i]; A[2*i] = v.x; A[2*i+1] = v.y; }
        A[14] = sa[lane * 6 + 14];
    }

    // bonds / normals for the 2 steps
    float vx[4], vy[4], vz[4];
    #pragma unroll
    for (int i = 0; i < 4; ++i) {
        vx[i] = A[3*i+3] - A[3*i];
        vy[i] = A[3*i+4] - A[3*i+1];
        vz[i] = A[3*i+5] - A[3*i+2];
    }
    float nx[3], ny[3], nz[3], Ln[3];
    #pragma unroll
    for (int i = 0; i < 3; ++i) {
        nx[i] = vy[i]*vz[i+1] - vz[i]*vy[i+1];
        ny[i] = vz[i]*vx[i+1] - vx[i]*vz[i+1];
        nz[i] = vx[i]*vy[i+1] - vy[i]*vx[i+1];
        Ln[i] = nx[i]*nx[i] + ny[i]*ny[i] + nz[i]*nz[i];
    }
    float Lv[3];
    #pragma unroll
    for (int i = 1; i < 3; ++i) Lv[i] = vx[i]*vx[i] + vy[i]*vy[i] + vz[i]*vz[i];
    const float th[2] = {th2.x, th2.y};

    // ---- build 2 step quats; D = q0⊗q1 ----
    Q4 q0, q1;
    BUILD_Q(0, q0); BUILD_Q(1, q1);
    const Q4 D = qmul(q0, q1);
    Q4 S = D;

    // ---- 6-round W64 inclusive quat scan via DPP ----
    const int rowi = lane & 15;
    #define QSCAN_ROUND(CTRL, COND)                                          \
    do {                                                                     \
        Q4 Qp;                                                               \
        Qp.w = dpp_mov<CTRL, 0xF>(S.w); Qp.x = dpp_mov<CTRL, 0xF>(S.x);      \
        Qp.y = dpp_mov<CTRL, 0xF>(S.y); Qp.z = dpp_mov<CTRL, 0xF>(S.z);      \
        if (COND) S = qmul(Qp, S);                                           \
    } while (0)
    QSCAN_ROUND(0x111, rowi >= 1);
    QSCAN_ROUND(0x112, rowi >= 2);
    QSCAN_ROUND(0x114, rowi >= 4);
    QSCAN_ROUND(0x118, rowi >= 8);
    QSCAN_ROUND(0x142, (lane & 16) != 0);   // rows 1,3: prepend lower-row total
    QSCAN_ROUND(0x143, (lane & 32) != 0);   // rows 2,3: prepend rows0-1 total
    #undef QSCAN_ROUND

    // exclusive prefix: E = S ⊗ conj(D)  (unit quats; lane0 -> identity)
    Q4 Dc; Dc.w = D.w; Dc.x = -D.x; Dc.y = -D.y; Dc.z = -D.z;
    const Q4 E  = qmul(S, Dc);
    const Q4 Pe = qmul(E, q0);          // R(P_{2l});  R(P_{2l+1}) = S

    // ---- d = R(P_k)·(pos0[k+3]-pos0[k+1]) ----
    float dex, dey, dez, dox, doy, doz;
    qrotv(Pe, A[9]-A[3],  A[10]-A[4], A[11]-A[5], dex, dey, dez);
    qrotv(S,  A[12]-A[6], A[13]-A[7], A[14]-A[8], dox, doy, doz);

    // ---- two float3 inclusive prefix sums via DPP (unconditional adds) ----
    float sex = dex, sey = dey, sez = dez;
    float sox = dox, soy = doy, soz = doz;
    #define SUM_ROUND(CTRL, RM)                                              \
    do {                                                                     \
        sex += dpp_mov<CTRL, RM>(sex); sey += dpp_mov<CTRL, RM>(sey);        \
        sez += dpp_mov<CTRL, RM>(sez);                                       \
        sox += dpp_mov<CTRL, RM>(sox); soy += dpp_mov<CTRL, RM>(soy);        \
        soz += dpp_mov<CTRL, RM>(soz);                                       \
    } while (0)
    SUM_ROUND(0x111, 0xF);
    SUM_ROUND(0x112, 0xF);
    SUM_ROUND(0x114, 0xF);
    SUM_ROUND(0x118, 0xF);
    SUM_ROUND(0x142, 0xA);   // rows 1,3 add lower-row total; rows 0,2 add 0
    SUM_ROUND(0x143, 0xC);   // rows 2,3 add rows0-1 total; rows 0,1 add 0
    #undef SUM_ROUND

    // final[2l+3] = pos0[1] + Se ; final[2l+4] = pos0[2] + So
    const float p1x = sa[3], p1y = sa[4], p1z = sa[5];
    const float p2x = sa[6], p2y = sa[7], p2z = sa[8];
    const float fex = p1x + sex, fey = p1y + sey, fez = p1z + sez;
    const float fox = p2x + sox, foy = p2y + soy, foz = p2z + soz;

    {
        float* op = &sout[6*lane + 9];
        op[0] = fex; op[1] = fey; op[2] = fez;   // atom 2l+3
        op[3] = fox; op[4] = foy; op[5] = foz;   // atom 2l+4
    }
    if (lane < 9) sout[lane] = sa[lane];   // atoms 0..2 never move

    // ---- F = P_127 (S@63); translation from final[130] = fo@63 ----
    float tFx = 0.f, tFy = 0.f, tFz = 0.f;
    if (lane == 63) {
        float rx, ry, rz;
        qrotv(S, sa[390], sa[391], sa[392], rx, ry, rz);   // R_F·pos0[130]
        tFx = fox - rx; tFy = foy - ry; tFz = foz - rz;
        // atom 131 = F(pos0[131])
        qrotv(S, sa[393], sa[394], sa[395], rx, ry, rz);
        sout[393] = rx + tFx; sout[394] = ry + tFy; sout[395] = rz + tFz;
    }
    Q4 Fq;
    Fq.w = __shfl(S.w, 63, 64); Fq.x = __shfl(S.x, 63, 64);
    Fq.y = __shfl(S.y, 63, 64); Fq.z = __shfl(S.z, 63, 64);
    const float Ftx = __shfl(tFx, 63, 64), Fty = __shfl(tFy, 63, 64), Ftz = __shfl(tFz, 63, 64);
    const float f00 = 1.f - 2.f*(Fq.y*Fq.y + Fq.z*Fq.z);
    const float f01 = 2.f*(Fq.x*Fq.y - Fq.w*Fq.z);
    const float f02 = 2.f*(Fq.x*Fq.z + Fq.w*Fq.y);
    const float f10 = 2.f*(Fq.x*Fq.y + Fq.w*Fq.z);
    const float f11 = 1.f - 2.f*(Fq.x*Fq.x + Fq.z*Fq.z);
    const float f12 = 2.f*(Fq.y*Fq.z - Fq.w*Fq.x);
    const float f20 = 2.f*(Fq.x*Fq.z - Fq.w*Fq.y);
    const float f21 = 2.f*(Fq.y*Fq.z + Fq.w*Fq.x);
    const float f22 = 1.f - 2.f*(Fq.x*Fq.x + Fq.y*Fq.y);

    // ---- store head (99 f4, coalesced) ----
    const float4* so4 = (const float4*)sout;
    ob4[lane] = so4[lane];
    if (ex) ob4[64 + lane] = so4[64 + lane];

    // ---- tail via LDS bounce: stage (coalesced) -> transform in place ->
    //      store (coalesced) ----
    float4* st4 = (float4*)st;
    st4[lane]       = Tr0;
    st4[64 + lane]  = Tr1;
    st4[128 + lane] = Tr2;
    st4[192 + lane] = Tr3;
    if (hasT4) st4[256 + lane] = Tr4;

    // float-granularity transform: atom i (0..379) at st[3i..3i+2];
    // stride-3 float addressing = 2 lanes/bank across wave64 (free).
    #pragma unroll
    for (int r2 = 0; r2 < 6; ++r2) {
        const int i = r2 * 64 + lane;
        if (r2 < 5 || lane < 60) {       // 380 tail atoms
            const float x = st[3*i], y = st[3*i+1], z = st[3*i+2];
            st[3*i]   = f00*x + f01*y + f02*z + Ftx;
            st[3*i+1] = f10*x + f11*y + f12*z + Fty;
            st[3*i+2] = f20*x + f21*y + f22*z + Ftz;
        }
    }

    ob4[99 + lane]        = st4[lane];
    ob4[99 + 64 + lane]   = st4[64 + lane];
    ob4[99 + 128 + lane]  = st4[128 + lane];
    ob4[99 + 192 + lane]  = st4[192 + lane];
    if (hasT4) ob4[99 + 256 + lane] = st4[256 + lane];
}

extern "C" void kernel_launch(void* const* d_in, const int* in_sizes, int n_in,
                              void* d_out, int out_size, void* d_ws, size_t ws_size,
                              hipStream_t stream) {
    const float* theta = (const float*)d_in[0];  // input (N,K) fp32
    const float* pos0  = (const float*)d_in[1];  // pos0 (N,M,3) fp32
    float* out = (float*)d_out;                  // (N,M,3) fp32
    dihedral_w64_coal_kernel<<<NMOL, TPB, 0, stream>>>(theta, pos0, out);
}